// Round 16
// baseline (1569.803 us; speedup 1.0000x reference)
//
#include <hip/hip_runtime.h>
#include <hip/hip_bf16.h>
#include <math.h>

#define B_ 16
#define N_ 128
#define S_ 129
#define HID_ 768
#define H_ 32
#define D_ 24
#define FFN_ 3072
#define L_ 12
#define M_ (B_*S_)   // 2064
#define SP_ 144
#define KP_ 160

#define WQKV_E ((size_t)2304*768)
#define WO_E   ((size_t)768*768)
#define W1_E   ((size_t)3072*768)
#define W2_E   ((size_t)768*3072)
#define WL_E_  (WQKV_E + WO_E + W1_E + W2_E)   // 7,077,888

typedef __attribute__((ext_vector_type(8))) short short8;
typedef __attribute__((ext_vector_type(4))) float f32x4;
typedef __hip_bfloat16 bf16;

#define VMCNT(n) asm volatile("s_waitcnt vmcnt(" #n ")" ::: "memory")
#define LDS_FENCE() asm volatile("" ::: "memory")

__device__ __forceinline__ void gload_lds16(const void* g, void* l) {
  __builtin_amdgcn_global_load_lds(
      (const __attribute__((address_space(1))) void*)g,
      (__attribute__((address_space(3))) void*)l, 16, 0, 0);
}

__device__ __forceinline__ float gld(const float* p) { return *p; }
__device__ __forceinline__ float gld(const bf16* p)  { return __bfloat162float(*p); }

// ============================================================
// gab boundary: row 0 (all kj) and col 0 (qi>=1): v = 2*ab + t
// ============================================================
__global__ __launch_bounds__(256) void gab_bound_kernel(
    const float* __restrict__ ab, const float* __restrict__ gtvd,
    float* __restrict__ gab, bf16* __restrict__ gabh)
{
  int u = blockIdx.x * 256 + threadIdx.x;
  const int PB = 2*S_ - 1;
  if (u >= B_*H_*PB) return;
  int p = u % PB;
  int bh = u / PB;
  int hh = bh % H_, b = bh / H_;
  int qi, kj;
  if (p < S_) { qi = 0; kj = p; } else { qi = p - S_ + 1; kj = 0; }
  float v = 2.0f * ab[(b*S_ + qi)*S_ + kj] + gtvd[hh];
  long g = ((long)(b*H_ + hh)*S_ + qi)*S_ + kj;
  if (gabh) gabh[g] = __float2bfloat16(v);
  else      gab[g]  = v;
}

// ============================================================
// F table (fp32)
// ============================================================
__global__ __launch_bounds__(256) void ftab_kernel(
    const float* __restrict__ eemb, const float* __restrict__ edis,
    float* __restrict__ F)
{
  __shared__ float em[8][32];
  int tid = threadIdx.x;
  int jl = tid >> 5, hh = tid & 31;
  int p = blockIdx.x * 8 + jl;
  bool valid = p < 5*1537;
  int d = valid ? p / 1537 : 0;
  int idx = valid ? p % 1537 : 0;
  em[jl][hh] = eemb[idx*32 + hh];
  float acc = 0.f;
#pragma unroll
  for (int hp = 0; hp < 32; ++hp)
    acc += em[jl][hp] * edis[d*1024 + hp*32 + hh];
  if (valid) F[(long)p*32 + hh] = acc * (1.0f/3.0f);
}

// ============================================================
// edge encoding + folded gab base for interior cells
// ============================================================
__global__ __launch_bounds__(256) void edge_kernel(
    const int* __restrict__ eidx, const float* __restrict__ F,
    const int* __restrict__ spos, const float* __restrict__ spemb,
    const float* __restrict__ ab, float* __restrict__ gab,
    bf16* __restrict__ gabh)
{
  __shared__ float outj[128][33];
  int tid = threadIdx.x;
  int jl = tid >> 5, hh = tid & 31;
  int bi = blockIdx.x;
  int b = bi >> 7, i = bi & 127;
  const int* erow = eidx + ((long)((b*N_ + i)*N_)) * 15;

  int er[15];
#pragma unroll
  for (int t = 0; t < 15; ++t) er[t] = erow[jl*15 + t];

  for (int ch = 0; ch < 16; ++ch) {
    int j = ch*8 + jl;
    int ern[15];
    if (ch < 15) {
#pragma unroll
      for (int t = 0; t < 15; ++t) ern[t] = erow[(j+8)*15 + t];
    }
    float acc = 0.f;
#pragma unroll
    for (int t = 0; t < 15; ++t)
      acc += F[((long)((t/3)*1537 + er[t]))*32 + hh];
    int sp0 = spos[(b*N_ + i)*N_ + j];
    int sp = (sp0 == 0) ? 1 : sp0;
    if (sp > 1) sp -= 1;
    if (sp > 5) sp = 5;
    outj[j][hh] = spemb[sp0*H_ + hh] + acc / (float)sp;
    if (ch < 15) {
#pragma unroll
      for (int t = 0; t < 15; ++t) er[t] = ern[t];
    }
  }
  __syncthreads();
  {
    int c = tid & 127;
    float base = 2.0f * ab[((long)(b*S_) + (i+1))*S_ + 1 + c];   // invariant over r
    for (int it = 0; it < 16; ++it) {
      int r = it*2 + (tid >> 7);
      float v = base + outj[c][r];
      long g = ((long)(b*H_ + r)*S_ + (i+1))*S_ + 1 + c;
      if (gabh) gabh[g] = __float2bfloat16(v);
      else      gab[g]  = v;
    }
  }
}

// ============================================================
// node features + fused layer-0 LN
// ============================================================
__global__ __launch_bounds__(256) void nodefeat_ln_kernel(
    const int* __restrict__ x, const int* __restrict__ indeg,
    const int* __restrict__ outdeg, const float* __restrict__ atom_emb,
    const float* __restrict__ in_emb, const float* __restrict__ out_emb,
    const float* __restrict__ gtok, const float* __restrict__ g,
    const float* __restrict__ bta, float* __restrict__ h,
    bf16* __restrict__ y)
{
  int row = blockIdx.x;
  int tid = threadIdx.x;
  int sidx = row % S_;
  int b = row / S_;
  float v[3];
  if (sidx == 0) {
#pragma unroll
    for (int j = 0; j < 3; ++j) v[j] = gtok[tid + j*256];
  } else {
    int n = sidx - 1;
    int id = indeg[b*N_ + n], od = outdeg[b*N_ + n];
    const int* xr = x + (b*N_ + n)*9;
    int xi[9];
#pragma unroll
    for (int e = 0; e < 9; ++e) xi[e] = xr[e];
#pragma unroll
    for (int j = 0; j < 3; ++j) {
      int c = tid + j*256;
      float a = in_emb[(long)id*HID_ + c] + out_emb[(long)od*HID_ + c];
#pragma unroll
      for (int e = 0; e < 9; ++e) a += atom_emb[(long)xi[e]*HID_ + c];
      v[j] = a;
    }
  }
  float* hr = h + (long)row*HID_;
#pragma unroll
  for (int j = 0; j < 3; ++j) hr[tid + j*256] = v[j];

  float s = v[0] + v[1] + v[2];
  float ss = v[0]*v[0] + v[1]*v[1] + v[2]*v[2];
  for (int off = 32; off > 0; off >>= 1) {
    s  += __shfl_xor(s, off);
    ss += __shfl_xor(ss, off);
  }
  __shared__ float rs[4], rss[4];
  int w = tid / 64;
  if ((tid & 63) == 0) { rs[w] = s; rss[w] = ss; }
  __syncthreads();
  s  = rs[0] + rs[1] + rs[2] + rs[3];
  ss = rss[0] + rss[1] + rss[2] + rss[3];
  float mean = s * (1.0f/768.0f);
  float var  = ss * (1.0f/768.0f) - mean*mean;
  float rstd = rsqrtf(var + 1e-5f);
  bf16* yr = y + (long)row*HID_;
#pragma unroll
  for (int j = 0; j < 3; ++j) {
    int c = tid + j*256;
    yr[c] = __float2bfloat16((v[j] - mean)*rstd*g[c] + bta[c]);
  }
}

// ============================================================
// LayerNorm fp32 -> bf16 (standalone, fallback path)
// ============================================================
__global__ __launch_bounds__(256) void ln_kernel(
    const float* __restrict__ in, const float* __restrict__ g,
    const float* __restrict__ bta, bf16* __restrict__ out)
{
  int row = blockIdx.x;
  int tid = threadIdx.x;
  const float* xr = in + (long)row * HID_;
  float x0 = xr[tid], x1 = xr[tid + 256], x2 = xr[tid + 512];
  float s = x0 + x1 + x2;
  float ss = x0*x0 + x1*x1 + x2*x2;
  for (int off = 32; off > 0; off >>= 1) {
    s  += __shfl_xor(s, off);
    ss += __shfl_xor(ss, off);
  }
  __shared__ float rs[4], rss[4];
  int w = tid / 64;
  if ((tid & 63) == 0) { rs[w] = s; rss[w] = ss; }
  __syncthreads();
  s  = rs[0] + rs[1] + rs[2] + rs[3];
  ss = rss[0] + rss[1] + rss[2] + rss[3];
  float mean = s * (1.0f/768.0f);
  float var  = ss * (1.0f/768.0f) - mean*mean;
  float rstd = rsqrtf(var + 1e-5f);
  bf16* orow = out + (long)row * HID_;
  orow[tid]       = __float2bfloat16((x0 - mean)*rstd*g[tid]       + bta[tid]);
  orow[tid + 256] = __float2bfloat16((x1 - mean)*rstd*g[tid + 256] + bta[tid + 256]);
  orow[tid + 512] = __float2bfloat16((x2 - mean)*rstd*g[tid + 512] + bta[tid + 512]);
}

// ============================================================
// fused: h += bias + sum_z part[z]; y = bf16(LN(h))
// ============================================================
template<int NZ>
__global__ __launch_bounds__(256) void addln_kernel(
    const float* __restrict__ part, const float* __restrict__ bias,
    const float* __restrict__ g, const float* __restrict__ bta,
    float* __restrict__ h, bf16* __restrict__ y)
{
  int row = blockIdx.x;
  int tid = threadIdx.x;
  const long MN = (long)M_*HID_;
  float* hr = h + (long)row*HID_;
  float v[3];
#pragma unroll
  for (int j = 0; j < 3; ++j) {
    int c = tid + j*256;
    float a = hr[c] + bias[c];
    const float* pp = part + (long)row*HID_ + c;
#pragma unroll
    for (int z = 0; z < NZ; ++z) a += pp[(long)z*MN];
    v[j] = a;
    hr[c] = a;
  }
  float s = v[0] + v[1] + v[2];
  float ss = v[0]*v[0] + v[1]*v[1] + v[2]*v[2];
  for (int off = 32; off > 0; off >>= 1) {
    s  += __shfl_xor(s, off);
    ss += __shfl_xor(ss, off);
  }
  __shared__ float rs[4], rss[4];
  int w = tid / 64;
  if ((tid & 63) == 0) { rs[w] = s; rss[w] = ss; }
  __syncthreads();
  s  = rs[0] + rs[1] + rs[2] + rs[3];
  ss = rss[0] + rss[1] + rss[2] + rss[3];
  float mean = s * (1.0f/768.0f);
  float var  = ss * (1.0f/768.0f) - mean*mean;
  float rstd = rsqrtf(var + 1e-5f);
  bf16* yr = y + (long)row*HID_;
#pragma unroll
  for (int j = 0; j < 3; ++j) {
    int c = tid + j*256;
    yr[c] = __float2bfloat16((v[j] - mean)*rstd*g[c] + bta[c]);
  }
}

// ============================================================
// weight converts
// ============================================================
__global__ __launch_bounds__(256) void wconv_kernel(
    const float* __restrict__ W, bf16* __restrict__ Out,
    int K, int N, float scale)
{
  __shared__ float tile[32][33];
  int bx = blockIdx.x * 32;
  int by = blockIdx.y * 32;
  int tx = threadIdx.x & 31, ty = threadIdx.x >> 5;
#pragma unroll
  for (int r = 0; r < 32; r += 8)
    tile[ty + r][tx] = W[(long)(by + ty + r)*N + bx + tx];
  __syncthreads();
#pragma unroll
  for (int r = 0; r < 32; r += 8)
    Out[(long)(bx + ty + r)*K + by + tx] = __float2bfloat16(tile[tx][ty + r] * scale);
}

__global__ __launch_bounds__(256) void qkvconv_kernel(
    const float* __restrict__ wq, const float* __restrict__ wk,
    const float* __restrict__ wv, bf16* __restrict__ Out, float scale)
{
  const float* W = blockIdx.z == 0 ? wq : blockIdx.z == 1 ? wk : wv;
  float sc = blockIdx.z == 0 ? scale : 1.0f;
  __shared__ float tile[32][33];
  int bx = blockIdx.x * 32;
  int by = blockIdx.y * 32;
  int tx = threadIdx.x & 31, ty = threadIdx.x >> 5;
#pragma unroll
  for (int r = 0; r < 32; r += 8)
    tile[ty + r][tx] = W[(long)(by + ty + r)*768 + bx + tx];
  __syncthreads();
  bf16* O = Out + (long)blockIdx.z * 768 * 768;
#pragma unroll
  for (int r = 0; r < 32; r += 8)
    O[(long)(bx + ty + r)*768 + by + tx] = __float2bfloat16(tile[tx][ty + r] * sc);
}

__global__ __launch_bounds__(256) void qkvconv_all_kernel(
    const float* __restrict__ wq, const float* __restrict__ wk,
    const float* __restrict__ wv, bf16* __restrict__ wbuf, float scale)
{
  int z = blockIdx.z;
  int l = z / 3, which = z % 3;
  const float* W = (which == 0 ? wq : which == 1 ? wk : wv) + (size_t)l*768*768;
  float sc = which == 0 ? scale : 1.0f;
  __shared__ float tile[32][33];
  int bx = blockIdx.x * 32;
  int by = blockIdx.y * 32;
  int tx = threadIdx.x & 31, ty = threadIdx.x >> 5;
#pragma unroll
  for (int r = 0; r < 32; r += 8)
    tile[ty + r][tx] = W[(long)(by + ty + r)*768 + bx + tx];
  __syncthreads();
  bf16* O = wbuf + (size_t)l*WL_E_ + (size_t)which*768*768;
#pragma unroll
  for (int r = 0; r < 32; r += 8)
    O[(long)(bx + ty + r)*768 + by + tx] = __float2bfloat16(tile[tx][ty + r] * sc);
}

__global__ __launch_bounds__(256) void wconv_all_kernel(
    const float* __restrict__ Wb, bf16* __restrict__ Ob,
    int K, int N, long inStride, long outStride)
{
  int z = blockIdx.z;
  const float* W = Wb + (size_t)z * inStride;
  bf16* Out = Ob + (size_t)z * outStride;
  __shared__ float tile[32][33];
  int bx = blockIdx.x * 32;
  int by = blockIdx.y * 32;
  int tx = threadIdx.x & 31, ty = threadIdx.x >> 5;
#pragma unroll
  for (int r = 0; r < 32; r += 8)
    tile[ty + r][tx] = W[(long)(by + ty + r)*N + bx + tx];
  __syncthreads();
#pragma unroll
  for (int r = 0; r < 32; r += 8)
    Out[(long)(bx + ty + r)*K + by + tx] = __float2bfloat16(tile[tx][ty + r]);
}

__global__ __launch_bounds__(256) void biasqkv_kernel(
    const float* __restrict__ bq, const float* __restrict__ bk,
    const float* __restrict__ bv, float* __restrict__ bqkv, float scale)
{
  int idx = blockIdx.x * 256 + threadIdx.x;
  if (idx >= L_*2304) return;
  int l = idx / 2304, n = idx % 2304;
  int p = n / 768, nn = n % 768;
  float v = (p == 0) ? bq[l*768 + nn]*scale : (p == 1) ? bk[l*768 + nn] : bv[l*768 + nn];
  bqkv[idx] = v;
}

// ============================================================
// bf16 MFMA GEMM 64x64 (fallback paths): ring-2, vmcnt 4/0.
// mode 0: bf16 out; 1: gelu->bf16; 2: +resid->fp32; 3: fp32 partial
// ============================================================
__device__ __forceinline__ void stage64k(
    const bf16* __restrict__ A, const bf16* __restrict__ Wt,
    bf16* Als, bf16* Bls, int bm, int bn, long ka, int M, int lda, int ldb, int tid)
{
  int r0 = tid >> 3, c = tid & 7;
#pragma unroll
  for (int p = 0; p < 2; ++p) {
    int row = p*32 + r0;
    int cs = c ^ (row & 7);
    int grow = bm + row; if (grow >= M) grow = M - 1;
    gload_lds16(A + (long)grow*lda + ka + cs*8, Als + (p*256 + (tid & ~63))*8);
    gload_lds16(Wt + (long)(bn + row)*ldb + ka + cs*8, Bls + (p*256 + (tid & ~63))*8);
  }
}

__global__ __launch_bounds__(256) void gemm64_kernel(
    const bf16* __restrict__ A, const bf16* __restrict__ Wt,
    const float* __restrict__ bias, const float* __restrict__ resid,
    void* __restrict__ Cout, int M, int N, int Klen, int lda, int ldb, int mode)
{
  constexpr int ASZ = 64*64;
  __shared__ bf16 Als[2*ASZ];
  __shared__ bf16 Bls[2*ASZ];
  int tid = threadIdx.x;
  int wid = tid >> 6, lane = tid & 63;

  int gx = gridDim.x;
  int nwg = gx * gridDim.y;
  int id = blockIdx.y * gx + blockIdx.x;
  int q = nwg >> 3, r = nwg & 7;
  int xcd = id & 7, off = id >> 3;
  int swz = (xcd < r) ? (xcd*(q+1) + off) : (r*(q+1) + (xcd - r)*q + off);
  int bm = (swz / gx) * 64, bn = (swz % gx) * 64;

  long koff = (long)blockIdx.z * Klen;
  int wr = wid >> 1, wc = wid & 1;
  int lr = lane & 15, kg = lane >> 4;

  int aoff[2][2], boff[2][2];
#pragma unroll
  for (int m = 0; m < 2; ++m) {
    int row = wr*32 + m*16 + lr;
#pragma unroll
    for (int hf = 0; hf < 2; ++hf) {
      int chunk = hf*4 + kg;
      aoff[m][hf] = (row*8 + (chunk ^ (row & 7)))*8;
    }
  }
#pragma unroll
  for (int n = 0; n < 2; ++n) {
    int col = wc*32 + n*16 + lr;
#pragma unroll
    for (int hf = 0; hf < 2; ++hf) {
      int chunk = hf*4 + kg;
      boff[n][hf] = (col*8 + (chunk ^ (col & 7)))*8;
    }
  }

  f32x4 acc[2][2];
#pragma unroll
  for (int m = 0; m < 2; ++m)
#pragma unroll
    for (int n = 0; n < 2; ++n)
      acc[m][n] = (f32x4){0.0f, 0.0f, 0.0f, 0.0f};

  int nt = Klen >> 6;
  stage64k(A, Wt, Als,       Bls,       bm, bn, koff,      M, lda, ldb, tid);
  stage64k(A, Wt, Als + ASZ, Bls + ASZ, bm, bn, koff + 64, M, lda, ldb, tid);

  int cur = 0;
  for (int t = 0; t < nt; ++t) {
    if (t + 1 < nt) VMCNT(4);
    else            VMCNT(0);
    __builtin_amdgcn_s_barrier();
    LDS_FENCE();
    bf16* Acur = Als + cur*ASZ;
    bf16* Bcur = Bls + cur*ASZ;
    short8 av[2][2], bv2[2][2];
#pragma unroll
    for (int m = 0; m < 2; ++m)
#pragma unroll
      for (int hf = 0; hf < 2; ++hf) av[m][hf] = *(const short8*)(Acur + aoff[m][hf]);
#pragma unroll
    for (int n = 0; n < 2; ++n)
#pragma unroll
      for (int hf = 0; hf < 2; ++hf) bv2[n][hf] = *(const short8*)(Bcur + boff[n][hf]);
#pragma unroll
    for (int hf = 0; hf < 2; ++hf)
#pragma unroll
      for (int m = 0; m < 2; ++m)
#pragma unroll
        for (int n = 0; n < 2; ++n)
          acc[m][n] = __builtin_amdgcn_mfma_f32_16x16x32_bf16(av[m][hf], bv2[n][hf], acc[m][n], 0, 0, 0);
    LDS_FENCE();
    __builtin_amdgcn_s_barrier();
    if (t + 2 < nt)
      stage64k(A, Wt, Als + cur*ASZ, Bls + cur*ASZ,
               bm, bn, koff + (long)(t+2)*64, M, lda, ldb, tid);
    cur ^= 1;
  }

#pragma unroll
  for (int n = 0; n < 2; ++n) {
    int col = bn + wc*32 + n*16 + lr;
    float bcol = (mode == 3) ? 0.0f : bias[col];
#pragma unroll
    for (int m = 0; m < 2; ++m) {
      f32x4 a = acc[m][n];
#pragma unroll
      for (int i = 0; i < 4; ++i) {
        int row = bm + wr*32 + m*16 + kg*4 + i;
        if (row < M) {
          float v = a[i] + bcol;
          if (mode == 1) v = 0.5f * v * (1.0f + erff(v * 0.70710678118654752f));
          if (mode == 2)
            ((float*)Cout)[(long)row*N + col] = v + resid[(long)row*N + col];
          else if (mode == 3)
            ((float*)Cout + (size_t)blockIdx.z*M*N)[(long)row*N + col] = v;
          else
            ((bf16*)Cout)[(long)row*N + col] = __float2bfloat16(v);
        }
      }
    }
  }
}

// ============================================================
// bf16 MFMA GEMM 128x128: 512 thr (8 waves, 2x4), wave tile 64x32,
// BK=64, ring-2 (64KB LDS), counted vmcnt 4/0, XOR swizzle, XCD swizzle.
// koff = blockIdx.z * Klen (split-K support).
// mode 0: bf16 out; 1: gelu->bf16; 3: fp32 partial (no bias)
// ============================================================
__device__ __forceinline__ void stage128k(
    const bf16* __restrict__ A, const bf16* __restrict__ Wt,
    bf16* Als, bf16* Bls, int bm, int bn, long ka, int M, int lda, int ldb, int tid)
{
  int r0 = tid >> 3, c = tid & 7;   // r0: 0..63, c: 0..7
#pragma unroll
  for (int p = 0; p < 2; ++p) {
    int row = p*64 + r0;
    int cs = c ^ (row & 7);
    int grow = bm + row; if (grow >= M) grow = M - 1;
    gload_lds16(A + (long)grow*lda + ka + cs*8, Als + (p*512 + (tid & ~63))*8);
    gload_lds16(Wt + (long)(bn + row)*ldb + ka + cs*8, Bls + (p*512 + (tid & ~63))*8);
  }
}

__global__ __launch_bounds__(512) void gemm128_kernel(
    const bf16* __restrict__ A, const bf16* __restrict__ Wt,
    const float* __restrict__ bias, void* __restrict__ Cout,
    int M, int N, int Klen, int lda, int ldb, int mode)
{
  constexpr int ASZ = 128*64;
  __shared__ bf16 Als[2*ASZ];
  __shared__ bf16 Bls[2*ASZ];
  int tid = threadIdx.x;
  int wid = tid >> 6, lane = tid & 63;

  int gx = gridDim.x;
  int nwg = gx * gridDim.y;
  int id = blockIdx.y * gx + blockIdx.x;
  int q = nwg >> 3, r = nwg & 7;
  int xcd = id & 7, off = id >> 3;
  int swz = (xcd < r) ? (xcd*(q+1) + off) : (r*(q+1) + (xcd - r)*q + off);
  int bm = (swz / gx) * 128, bn = (swz % gx) * 128;

  long koff = (long)blockIdx.z * Klen;
  int wr = wid >> 2, wc = wid & 3;           // 2 x 4 waves
  int lr = lane & 15, kg = lane >> 4;

  int aoff[4][2], boff[2][2];
#pragma unroll
  for (int m = 0; m < 4; ++m) {
    int row = wr*64 + m*16 + lr;
#pragma unroll
    for (int hf = 0; hf < 2; ++hf) {
      int chunk = hf*4 + kg;
      aoff[m][hf] = (row*8 + (chunk ^ (row & 7)))*8;
    }
  }
#pragma unroll
  for (int n = 0; n < 2; ++n) {
    int col = wc*32 + n*16 + lr;
#pragma unroll
    for (int hf = 0; hf < 2; ++hf) {
      int chunk = hf*4 + kg;
      boff[n][hf] = (col*8 + (chunk ^ (col & 7)))*8;
    }
  }

  f32x4 acc[4][2];
#pragma unroll
  for (int m = 0; m < 4; ++m)
#pragma unroll
    for (int n = 0; n < 2; ++n)
      acc[m][n] = (f32x4){0.0f, 0.0f, 0.0f, 0.0f};

  int nt = Klen >> 6;
  stage128k(A, Wt, Als,       Bls,       bm, bn, koff,      M, lda, ldb, tid);
  stage128k(A, Wt, Als + ASZ, Bls + ASZ, bm, bn, koff + 64, M, lda, ldb, tid);

  int cur = 0;
  for (int t = 0; t < nt; ++t) {
    if (t + 1 < nt) VMCNT(4);
    else            VMCNT(0);
    __builtin_amdgcn_s_barrier();
    LDS_FENCE();
    bf16* Acur = Als + cur*ASZ;
    bf16* Bcur = Bls + cur*ASZ;
    short8 av[4][2], bv2[2][2];
#pragma unroll
    for (int m = 0; m < 4; ++m)
#pragma unroll
      for (int hf = 0; hf < 2; ++hf) av[m][hf] = *(const short8*)(Acur + aoff[m][hf]);
#pragma unroll
    for (int n = 0; n < 2; ++n)
#pragma unroll
      for (int hf = 0; hf < 2; ++hf) bv2[n][hf] = *(const short8*)(Bcur + boff[n][hf]);
#pragma unroll
    for (int hf = 0; hf < 2; ++hf)
#pragma unroll
      for (int m = 0; m < 4; ++m)
#pragma unroll
        for (int n = 0; n < 2; ++n)
          acc[m][n] = __builtin_amdgcn_mfma_f32_16x16x32_bf16(av[m][hf], bv2[n][hf], acc[m][n], 0, 0, 0);
    LDS_FENCE();
    __builtin_amdgcn_s_barrier();
    if (t + 2 < nt)
      stage128k(A, Wt, Als + cur*ASZ, Bls + cur*ASZ,
                bm, bn, koff + (long)(t+2)*64, M, lda, ldb, tid);
    cur ^= 1;
  }

#pragma unroll
  for (int n = 0; n < 2; ++n) {
    int col = bn + wc*32 + n*16 + lr;
    float bcol = (mode == 3) ? 0.0f : bias[col];
#pragma unroll
    for (int m = 0; m < 4; ++m) {
      f32x4 a = acc[m][n];
#pragma unroll
      for (int i = 0; i < 4; ++i) {
        int row = bm + wr*64 + m*16 + kg*4 + i;
        if (row < M) {
          float v = a[i] + bcol;
          if (mode == 1) v = 0.5f * v * (1.0f + erff(v * 0.70710678118654752f));
          if (mode == 3)
            ((float*)Cout + (size_t)blockIdx.z*M*N)[(long)row*N + col] = v;
          else
            ((bf16*)Cout)[(long)row*N + col] = __float2bfloat16(v);
        }
      }
    }
  }
}

// ============================================================
// MFMA fused attention: ONE 8-wave block per (b,h). (R13-proven)
// ============================================================
template<typename GT>
__global__ __launch_bounds__(512) void attn_kernel(
    const bf16* __restrict__ qkv, const GT* __restrict__ gab,
    bf16* __restrict__ ob)
{
  int bh = blockIdx.x;
  int b = bh >> 5, hh = bh & 31;
  __shared__ bf16 kl[SP_*32];
  __shared__ bf16 vt[32*KP_];
  __shared__ bf16 pl[8][16*KP_];
  int tid = threadIdx.x;
  int wv = tid >> 6, lane = tid & 63;
  const short8 z8 = (short8){0,0,0,0,0,0,0,0};

  for (int idx = tid; idx < 32*KP_/8; idx += 512)
    *(short8*)&vt[idx*8] = z8;
  const bf16* qbase = qkv + (long)b*S_*2304 + hh*24;
  for (int u = tid; u < SP_*4; u += 512) {
    int row = u >> 2, c8 = u & 3;
    short8 kv = z8;
    if (row < S_ && c8 < 3)
      kv = *(const short8*)(qbase + (long)row*2304 + 768 + c8*8);
    int cs = c8 ^ ((row >> 1) & 3);
    *(short8*)&kl[row*32 + cs*8] = kv;
  }
  __syncthreads();
  for (int u = tid; u < S_*3; u += 512) {
    int kj = u / 3, c8 = u % 3;
    short8 vv = *(const short8*)(qbase + (long)kj*2304 + 1536 + c8*8);
    int kb = kj & 7, kh = kj >> 3;
#pragma unroll
    for (int e = 0; e < 8; ++e) {
      int c = c8*8 + e;
      int ch = kh ^ ((c >> 1) & 3);
      short sv = vv[e];
      vt[c*KP_ + ch*8 + kb] = *reinterpret_cast<bf16*>(&sv);
    }
  }
  __syncthreads();

  int l15 = lane & 15, l4 = lane >> 4;

  short8 bvf[5][2];
#pragma unroll
  for (int kc = 0; kc < 5; ++kc)
#pragma unroll
    for (int ntc = 0; ntc < 2; ++ntc) {
      int col = ntc*16 + l15;
      int ch = (kc*4 + l4) ^ ((col >> 1) & 3);
      bvf[kc][ntc] = *(const short8*)&vt[col*KP_ + ch*8];
    }

  bf16* plw = pl[wv];
  for (int idx = lane; idx < 16*KP_/8; idx += 64)
    *(short8*)&plw[idx*8] = z8;

  const GT* gb = gab + (long)(b*H_ + hh)*S_*S_;

  for (int rep = 0; rep < 2; ++rep) {
    int mf = (rep == 0) ? wv : ((wv == 0) ? 8 : -1);
    if (mf < 0) continue;
    int qb0 = mf * 16;
    int qrow = qb0 + l15;
    short8 aq = z8;
    if (qrow < S_ && l4 < 3)
      aq = *(const short8*)(qbase + (long)qrow*2304 + l4*8);
    f32x4 sc[9];
#pragma unroll
    for (int nt = 0; nt < 9; ++nt) {
      int krow = nt*16 + l15;
      int kch = l4 ^ ((krow >> 1) & 3);
      short8 bk = *(const short8*)&kl[krow*32 + kch*8];
      sc[nt] = __builtin_amdgcn_mfma_f32_16x16x32_bf16(aq, bk, (f32x4){0,0,0,0}, 0, 0, 0);
    }
    float mx[4] = {-1e30f,-1e30f,-1e30f,-1e30f};
#pragma unroll
    for (int nt = 0; nt < 9; ++nt) {
      int kj = nt*16 + l15;
      int kjc = kj < S_ ? kj : 0;
#pragma unroll
      for (int i = 0; i < 4; ++i) {
        int q = qb0 + l4*4 + i;
        int qc = q < S_ ? q : 0;
        float v = sc[nt][i] + gld(&gb[(long)qc*S_ + kjc]);
        if (kj >= S_) v = -1e30f;
        sc[nt][i] = v;
        mx[i] = fmaxf(mx[i], v);
      }
    }
#pragma unroll
    for (int i = 0; i < 4; ++i) {
      mx[i] = fmaxf(mx[i], __shfl_xor(mx[i], 1));
      mx[i] = fmaxf(mx[i], __shfl_xor(mx[i], 2));
      mx[i] = fmaxf(mx[i], __shfl_xor(mx[i], 4));
      mx[i] = fmaxf(mx[i], __shfl_xor(mx[i], 8));
    }
    float sum[4] = {0.f,0.f,0.f,0.f};
#pragma unroll
    for (int nt = 0; nt < 9; ++nt)
#pragma unroll
      for (int i = 0; i < 4; ++i) {
        float e = __expf(sc[nt][i] - mx[i]);
        sc[nt][i] = e;
        sum[i] += e;
      }
#pragma unroll
    for (int i = 0; i < 4; ++i) {
      sum[i] += __shfl_xor(sum[i], 1);
      sum[i] += __shfl_xor(sum[i], 2);
      sum[i] += __shfl_xor(sum[i], 4);
      sum[i] += __shfl_xor(sum[i], 8);
    }
#pragma unroll
    for (int nt = 0; nt < 9; ++nt) {
      int kj = nt*16 + l15;
#pragma unroll
      for (int i = 0; i < 4; ++i) {
        int q = l4*4 + i;
        int ch = (kj >> 3) ^ ((q >> 1) & 3);
        plw[q*KP_ + ch*8 + (kj & 7)] = __float2bfloat16(sc[nt][i]);
      }
    }
    f32x4 av[2] = {(f32x4){0,0,0,0}, (f32x4){0,0,0,0}};
#pragma unroll
    for (int kc = 0; kc < 5; ++kc) {
      int ch = (kc*4 + l4) ^ ((l15 >> 1) & 3);
      short8 ap = *(const short8*)&plw[l15*KP_ + ch*8];
#pragma unroll
      for (int ntc = 0; ntc < 2; ++ntc)
        av[ntc] = __builtin_amdgcn_mfma_f32_16x16x32_bf16(ap, bvf[kc][ntc], av[ntc], 0, 0, 0);
    }
#pragma unroll
    for (int ntc = 0; ntc < 2; ++ntc) {
      int c = ntc*16 + l15;
      if (c < 24) {
#pragma unroll
        for (int i = 0; i < 4; ++i) {
          int q = qb0 + l4*4 + i;
          if (q < S_)
            ob[(long)(b*S_ + q)*768 + hh*24 + c] = __float2bfloat16(av[ntc][i] / sum[i]);
        }
      }
    }
  }
}

// ============================================================
// final
// ============================================================
__global__ __launch_bounds__(256) void final_kernel(
    const float* __restrict__ h, const float* __restrict__ fg,
    const float* __restrict__ fb, const float* __restrict__ pw,
    const float* __restrict__ pb, float* __restrict__ out)
{
  int b = blockIdx.x;
  int tid = threadIdx.x;
  const float* xr = h + (long)b * S_ * HID_;
  float x0 = xr[tid], x1 = xr[tid + 256], x2 = xr[tid + 512];
  float s = x0 + x1 + x2;
  float ss = x0*x0 + x1*x1 + x2*x2;
  for (int off = 32; off > 0; off >>= 1) {
    s  += __shfl_xor(s, off);
    ss += __shfl_xor(ss, off);
  }
  __shared__ float rs[4], rss[4], rd[4];
  int w = tid / 64;
  if ((tid & 63) == 0) { rs[w] = s; rss[w] = ss; }
  __syncthreads();
  s  = rs[0] + rs[1] + rs[2] + rs[3];
  ss = rss[0] + rss[1] + rss[2] + rss[3];
  float mean = s * (1.0f/768.0f);
  float var  = ss * (1.0f/768.0f) - mean*mean;
  float rstd = rsqrtf(var + 1e-5f);
  float d0 = ((x0 - mean)*rstd*fg[tid]       + fb[tid])       * pw[tid];
  float d1 = ((x1 - mean)*rstd*fg[tid + 256] + fb[tid + 256]) * pw[tid + 256];
  float d2 = ((x2 - mean)*rstd*fg[tid + 512] + fb[tid + 512]) * pw[tid + 512];
  float pd = d0 + d1 + d2;
  for (int off = 32; off > 0; off >>= 1) pd += __shfl_xor(pd, off);
  if ((tid & 63) == 0) rd[w] = pd;
  __syncthreads();
  if (tid == 0) out[b] = rd[0] + rd[1] + rd[2] + rd[3] + pb[0];
}

// ============================================================
extern "C" void kernel_launch(void* const* d_in, const int* in_sizes, int n_in,
                              void* d_out, int out_size, void* d_ws, size_t ws_size,
                              hipStream_t stream)
{
  const float* attn_bias   = (const float*)d_in[0];
  const int*   spatial_pos = (const int*)d_in[1];
  const int*   x           = (const int*)d_in[2];
  const int*   in_degree   = (const int*)d_in[3];
  const int*   out_degree  = (const int*)d_in[4];
  const int*   edge_input  = (const int*)d_in[5];
  const float* atom_emb    = (const float*)d_in[6];
  const float* edge_emb    = (const float*)d_in[7];
  const float* edge_dis    = (const float*)d_in[8];
  const float* spatial_emb = (const float*)d_in[9];
  const float* in_deg_emb  = (const float*)d_in[10];
  const float* out_deg_emb = (const float*)d_in[11];
  const float* graph_token = (const float*)d_in[12];
  const float* gt_vd       = (const float*)d_in[13];
  const float* ln1_g = (const float*)d_in[14];
  const float* ln1_b = (const float*)d_in[15];
  const float* wq = (const float*)d_in[16];
  const float* bq = (const float*)d_in[17];
  const float* wk = (const float*)d_in[18];
  const float* bk = (const float*)d_in[19];
  const float* wv = (const float*)d_in[20];
  const float* bv = (const float*)d_in[21];
  const float* wo = (const float*)d_in[22];
  const float* bo = (const float*)d_in[23];
  const float* ln2_g = (const float*)d_in[24];
  const float* ln2_b = (const float*)d_in[25];
  const float* w1 = (const float*)d_in[26];
  const float* b1 = (const float*)d_in[27];
  const float* w2 = (const float*)d_in[28];
  const float* b2 = (const float*)d_in[29];
  const float* final_g = (const float*)d_in[30];
  const float* final_b = (const float*)d_in[31];
  const float* proj_w  = (const float*)d_in[32];
  const float* proj_b  = (const float*)d_in[33];

  float* out = (float*)d_out;

  const float scale = 0.20412414523193154f;  // 24^-0.5
  const long GAB_N = (long)B_*H_*S_*S_;      // 8,520,192
  const size_t PART_B = (size_t)4 * M_ * 768 * 4;   // 25.4 MB

  char* dws = (char*)d_ws;
  char* p = dws;
  float* gab  = (float*)p;  p += GAB_N*4;
  float* h    = (float*)p;  p += (long)M_*HID_*4;
  bf16*  y    = (bf16*)p;   p += (long)M_*HID_*2;
  bf16*  qkv  = (bf16*)p;   // ffn aliases qkv+ob
  bf16*  ffn  = qkv;
  p += (long)M_*2304*2;
  bf16*  ob   = (bf16*)p;   p += (long)M_*HID_*2;
  float* Ftab = (float*)p;  p += (long)5*1537*32*4;
  float* bqkv = (float*)p;  p += (long)L_*2304*4;

  // optional split-K partial buffer
  float* part = (float*)p;
  bool psplit = ws_size >= (size_t)(p - dws) + PART_B + WL_E_*2;
  if (psplit) p += PART_B;
  // optional bf16 gab
  bf16* gabh = (bf16*)p;
  bool g16 = ws_size >= (size_t)(p - dws) + (size_t)GAB_N*2 + WL_E_*2;
  if (g16) p += GAB_N*2;
  // weight buffer
  bf16* wbuf = (bf16*)p;
  bool full = ws_size >= (size_t)(p - dws) + (size_t)L_ * WL_E_ * 2;

  // ---- setup ----
  const int PB = 2*S_ - 1;
  gab_bound_kernel<<<(B_*H_*PB + 255)/256, 256, 0, stream>>>(
      attn_bias, gt_vd, gab, g16 ? gabh : nullptr);
  ftab_kernel<<<(5*1537 + 7)/8, 256, 0, stream>>>(edge_emb, edge_dis, Ftab);
  edge_kernel<<<B_*N_, 256, 0, stream>>>(
      edge_input, Ftab, spatial_pos, spatial_emb, attn_bias, gab,
      g16 ? gabh : nullptr);
  nodefeat_ln_kernel<<<M_, 256, 0, stream>>>(
      x, in_degree, out_degree, atom_emb, in_deg_emb, out_deg_emb, graph_token,
      ln1_g, ln1_b, h, y);
  biasqkv_kernel<<<(L_*2304 + 255)/256, 256, 0, stream>>>(bq, bk, bv, bqkv, scale);

  if (full) {
    qkvconv_all_kernel<<<dim3(24,24,3*L_), 256, 0, stream>>>(wq, wk, wv, wbuf, scale);
    wconv_all_kernel<<<dim3(24,24,L_), 256, 0, stream>>>(
        wo, wbuf + WQKV_E, 768, 768, (long)768*768, (long)WL_E_);
    wconv_all_kernel<<<dim3(96,24,L_), 256, 0, stream>>>(
        w1, wbuf + WQKV_E + WO_E, 768, 3072, (long)768*3072, (long)WL_E_);
    wconv_all_kernel<<<dim3(24,96,L_), 256, 0, stream>>>(
        w2, wbuf + WQKV_E + WO_E + W1_E, 3072, 768, (long)3072*768, (long)WL_E_);
  }

  const int MT  = (M_ + 63)/64;              // 33
  const int MT2 = (M_ + 127)/128;            // 17
  dim3 gQKV(2304/128, MT2);                  // 18 x 17 (128^2)
  dim3 gF1 (3072/128, MT2);                  // 24 x 17 (128^2)
  dim3 gO4 (768/128, MT2, 4);                // split-K4 (O-proj, 128^2, Klen=192)
  dim3 gO  (768/64,  MT);
  dim3 gF2 (768/128, MT2, 4);                // split-K4 (FFN2, 128^2, Klen=768)
  dim3 gF2f(768/64,  MT);                    // fallback (no psplit)
  dim3 cQKV(768/32, 768/32, 3);
  dim3 cO  (768/32, 768/32);
  dim3 cW1 (3072/32, 768/32);
  dim3 cW2 (768/32, 3072/32);

  auto wptr = [&](int l) { return wbuf + (full ? (size_t)l : 0) * WL_E_; };
  auto conv = [&](int l) {
    bf16* W = wptr(l);
    qkvconv_kernel<<<cQKV, 256, 0, stream>>>(
        wq + (size_t)l*HID_*HID_, wk + (size_t)l*HID_*HID_, wv + (size_t)l*HID_*HID_,
        W, scale);
    wconv_kernel<<<cO, 256, 0, stream>>>(wo + (size_t)l*HID_*HID_, W + WQKV_E, 768, 768, 1.0f);
    wconv_kernel<<<cW1, 256, 0, stream>>>(w1 + (size_t)l*HID_*FFN_, W + WQKV_E + WO_E, 768, 3072, 1.0f);
    wconv_kernel<<<cW2, 256, 0, stream>>>(w2 + (size_t)l*FFN_*HID_, W + WQKV_E + WO_E + W1_E, 3072, 768, 1.0f);
  };

  for (int l = 0; l < L_; ++l) {
    if (!full) conv(l);
    bf16* W = wptr(l);
    bf16* Wqkvt = W;
    bf16* Wot   = W + WQKV_E;
    bf16* W1t   = W + WQKV_E + WO_E;
    bf16* W2t   = W + WQKV_E + WO_E + W1_E;

    if (l > 0 && !psplit)
      ln_kernel<<<M_, 256, 0, stream>>>(h, ln1_g + l*HID_, ln1_b + l*HID_, y);

    gemm128_kernel<<<gQKV, 512, 0, stream>>>(
        y, Wqkvt, bqkv + l*2304, qkv, M_, 2304, 768, 768, 768, 0);
    if (g16)
      attn_kernel<bf16><<<B_*H_, 512, 0, stream>>>(qkv, gabh, ob);
    else
      attn_kernel<float><<<B_*H_, 512, 0, stream>>>(qkv, gab, ob);

    if (psplit) {
      gemm128_kernel<<<gO4, 512, 0, stream>>>(
          ob, Wot, nullptr, part, M_, 768, 192, 768, 768, 3);
      addln_kernel<4><<<M_, 256, 0, stream>>>(
          part, bo + l*HID_, ln2_g + l*HID_, ln2_b + l*HID_, h, y);
    } else {
      gemm64_kernel<<<gO, 256, 0, stream>>>(
          ob, Wot, bo + l*HID_, h, h, M_, 768, 768, 768, 768, 2);
      ln_kernel<<<M_, 256, 0, stream>>>(h, ln2_g + l*HID_, ln2_b + l*HID_, y);
    }

    gemm128_kernel<<<gF1, 512, 0, stream>>>(
        y, W1t, b1 + l*FFN_, ffn, M_, 3072, 768, 768, 768, 1);

    if (psplit) {
      gemm128_kernel<<<gF2, 512, 0, stream>>>(
          ffn, W2t, nullptr, part, M_, 768, 768, 3072, 3072, 3);
      int ln = (l + 1 < L_) ? l + 1 : 0;   // last layer: y unused afterward
      addln_kernel<4><<<M_, 256, 0, stream>>>(
          part, b2 + l*HID_, ln1_g + ln*HID_, ln1_b + ln*HID_, h, y);
    } else {
      gemm64_kernel<<<gF2f, 256, 0, stream>>>(
          ffn, W2t, b2 + l*HID_, h, h, M_, 768, 3072, 3072, 3072, 2);
    }
  }

  final_kernel<<<B_, 256, 0, stream>>>(h, final_g, final_b, proj_w, proj_b, out);
}

// Round 17
// 1528.467 us; speedup vs baseline: 1.0270x; 1.0270x over previous
//
#include <hip/hip_runtime.h>
#include <hip/hip_bf16.h>
#include <math.h>

#define B_ 16
#define N_ 128
#define S_ 129
#define HID_ 768
#define H_ 32
#define D_ 24
#define FFN_ 3072
#define L_ 12
#define M_ (B_*S_)   // 2064
#define SP_ 144
#define KP_ 160

#define WQKV_E ((size_t)2304*768)
#define WO_E   ((size_t)768*768)
#define W1_E   ((size_t)3072*768)
#define W2_E   ((size_t)768*3072)
#define WL_E_  (WQKV_E + WO_E + W1_E + W2_E)   // 7,077,888

typedef __attribute__((ext_vector_type(8))) short short8;
typedef __attribute__((ext_vector_type(4))) float f32x4;
typedef __hip_bfloat16 bf16;

#define VMCNT(n) asm volatile("s_waitcnt vmcnt(" #n ")" ::: "memory")
#define LDS_FENCE() asm volatile("" ::: "memory")

__device__ __forceinline__ void gload_lds16(const void* g, void* l) {
  __builtin_amdgcn_global_load_lds(
      (const __attribute__((address_space(1))) void*)g,
      (__attribute__((address_space(3))) void*)l, 16, 0, 0);
}

__device__ __forceinline__ float gld(const float* p) { return *p; }
__device__ __forceinline__ float gld(const bf16* p)  { return __bfloat162float(*p); }

// ============================================================
// gab boundary: row 0 (all kj) and col 0 (qi>=1): v = 2*ab + t
// ============================================================
__global__ __launch_bounds__(256) void gab_bound_kernel(
    const float* __restrict__ ab, const float* __restrict__ gtvd,
    float* __restrict__ gab, bf16* __restrict__ gabh)
{
  int u = blockIdx.x * 256 + threadIdx.x;
  const int PB = 2*S_ - 1;
  if (u >= B_*H_*PB) return;
  int p = u % PB;
  int bh = u / PB;
  int hh = bh % H_, b = bh / H_;
  int qi, kj;
  if (p < S_) { qi = 0; kj = p; } else { qi = p - S_ + 1; kj = 0; }
  float v = 2.0f * ab[(b*S_ + qi)*S_ + kj] + gtvd[hh];
  long g = ((long)(b*H_ + hh)*S_ + qi)*S_ + kj;
  if (gabh) gabh[g] = __float2bfloat16(v);
  else      gab[g]  = v;
}

// ============================================================
// F table (fp32)
// ============================================================
__global__ __launch_bounds__(256) void ftab_kernel(
    const float* __restrict__ eemb, const float* __restrict__ edis,
    float* __restrict__ F)
{
  __shared__ float em[8][32];
  int tid = threadIdx.x;
  int jl = tid >> 5, hh = tid & 31;
  int p = blockIdx.x * 8 + jl;
  bool valid = p < 5*1537;
  int d = valid ? p / 1537 : 0;
  int idx = valid ? p % 1537 : 0;
  em[jl][hh] = eemb[idx*32 + hh];
  float acc = 0.f;
#pragma unroll
  for (int hp = 0; hp < 32; ++hp)
    acc += em[jl][hp] * edis[d*1024 + hp*32 + hh];
  if (valid) F[(long)p*32 + hh] = acc * (1.0f/3.0f);
}

// ============================================================
// edge encoding + folded gab base for interior cells
// ============================================================
__global__ __launch_bounds__(256) void edge_kernel(
    const int* __restrict__ eidx, const float* __restrict__ F,
    const int* __restrict__ spos, const float* __restrict__ spemb,
    const float* __restrict__ ab, float* __restrict__ gab,
    bf16* __restrict__ gabh)
{
  __shared__ float outj[128][33];
  int tid = threadIdx.x;
  int jl = tid >> 5, hh = tid & 31;
  int bi = blockIdx.x;
  int b = bi >> 7, i = bi & 127;
  const int* erow = eidx + ((long)((b*N_ + i)*N_)) * 15;

  int er[15];
#pragma unroll
  for (int t = 0; t < 15; ++t) er[t] = erow[jl*15 + t];

  for (int ch = 0; ch < 16; ++ch) {
    int j = ch*8 + jl;
    int ern[15];
    if (ch < 15) {
#pragma unroll
      for (int t = 0; t < 15; ++t) ern[t] = erow[(j+8)*15 + t];
    }
    float acc = 0.f;
#pragma unroll
    for (int t = 0; t < 15; ++t)
      acc += F[((long)((t/3)*1537 + er[t]))*32 + hh];
    int sp0 = spos[(b*N_ + i)*N_ + j];
    int sp = (sp0 == 0) ? 1 : sp0;
    if (sp > 1) sp -= 1;
    if (sp > 5) sp = 5;
    outj[j][hh] = spemb[sp0*H_ + hh] + acc / (float)sp;
    if (ch < 15) {
#pragma unroll
      for (int t = 0; t < 15; ++t) er[t] = ern[t];
    }
  }
  __syncthreads();
  {
    int c = tid & 127;
    float base = 2.0f * ab[((long)(b*S_) + (i+1))*S_ + 1 + c];   // invariant over r
    for (int it = 0; it < 16; ++it) {
      int r = it*2 + (tid >> 7);
      float v = base + outj[c][r];
      long g = ((long)(b*H_ + r)*S_ + (i+1))*S_ + 1 + c;
      if (gabh) gabh[g] = __float2bfloat16(v);
      else      gab[g]  = v;
    }
  }
}

// ============================================================
// node features + fused layer-0 LN
// ============================================================
__global__ __launch_bounds__(256) void nodefeat_ln_kernel(
    const int* __restrict__ x, const int* __restrict__ indeg,
    const int* __restrict__ outdeg, const float* __restrict__ atom_emb,
    const float* __restrict__ in_emb, const float* __restrict__ out_emb,
    const float* __restrict__ gtok, const float* __restrict__ g,
    const float* __restrict__ bta, float* __restrict__ h,
    bf16* __restrict__ y)
{
  int row = blockIdx.x;
  int tid = threadIdx.x;
  int sidx = row % S_;
  int b = row / S_;
  float v[3];
  if (sidx == 0) {
#pragma unroll
    for (int j = 0; j < 3; ++j) v[j] = gtok[tid + j*256];
  } else {
    int n = sidx - 1;
    int id = indeg[b*N_ + n], od = outdeg[b*N_ + n];
    const int* xr = x + (b*N_ + n)*9;
    int xi[9];
#pragma unroll
    for (int e = 0; e < 9; ++e) xi[e] = xr[e];
#pragma unroll
    for (int j = 0; j < 3; ++j) {
      int c = tid + j*256;
      float a = in_emb[(long)id*HID_ + c] + out_emb[(long)od*HID_ + c];
#pragma unroll
      for (int e = 0; e < 9; ++e) a += atom_emb[(long)xi[e]*HID_ + c];
      v[j] = a;
    }
  }
  float* hr = h + (long)row*HID_;
#pragma unroll
  for (int j = 0; j < 3; ++j) hr[tid + j*256] = v[j];

  float s = v[0] + v[1] + v[2];
  float ss = v[0]*v[0] + v[1]*v[1] + v[2]*v[2];
  for (int off = 32; off > 0; off >>= 1) {
    s  += __shfl_xor(s, off);
    ss += __shfl_xor(ss, off);
  }
  __shared__ float rs[4], rss[4];
  int w = tid / 64;
  if ((tid & 63) == 0) { rs[w] = s; rss[w] = ss; }
  __syncthreads();
  s  = rs[0] + rs[1] + rs[2] + rs[3];
  ss = rss[0] + rss[1] + rss[2] + rss[3];
  float mean = s * (1.0f/768.0f);
  float var  = ss * (1.0f/768.0f) - mean*mean;
  float rstd = rsqrtf(var + 1e-5f);
  bf16* yr = y + (long)row*HID_;
#pragma unroll
  for (int j = 0; j < 3; ++j) {
    int c = tid + j*256;
    yr[c] = __float2bfloat16((v[j] - mean)*rstd*g[c] + bta[c]);
  }
}

// ============================================================
// LayerNorm fp32 -> bf16 (standalone, fallback path)
// ============================================================
__global__ __launch_bounds__(256) void ln_kernel(
    const float* __restrict__ in, const float* __restrict__ g,
    const float* __restrict__ bta, bf16* __restrict__ out)
{
  int row = blockIdx.x;
  int tid = threadIdx.x;
  const float* xr = in + (long)row * HID_;
  float x0 = xr[tid], x1 = xr[tid + 256], x2 = xr[tid + 512];
  float s = x0 + x1 + x2;
  float ss = x0*x0 + x1*x1 + x2*x2;
  for (int off = 32; off > 0; off >>= 1) {
    s  += __shfl_xor(s, off);
    ss += __shfl_xor(ss, off);
  }
  __shared__ float rs[4], rss[4];
  int w = tid / 64;
  if ((tid & 63) == 0) { rs[w] = s; rss[w] = ss; }
  __syncthreads();
  s  = rs[0] + rs[1] + rs[2] + rs[3];
  ss = rss[0] + rss[1] + rss[2] + rss[3];
  float mean = s * (1.0f/768.0f);
  float var  = ss * (1.0f/768.0f) - mean*mean;
  float rstd = rsqrtf(var + 1e-5f);
  bf16* orow = out + (long)row * HID_;
  orow[tid]       = __float2bfloat16((x0 - mean)*rstd*g[tid]       + bta[tid]);
  orow[tid + 256] = __float2bfloat16((x1 - mean)*rstd*g[tid + 256] + bta[tid + 256]);
  orow[tid + 512] = __float2bfloat16((x2 - mean)*rstd*g[tid + 512] + bta[tid + 512]);
}

// ============================================================
// fused: h += bias + sum_z part[z]; y = bf16(LN(h))
// ============================================================
template<int NZ>
__global__ __launch_bounds__(256) void addln_kernel(
    const float* __restrict__ part, const float* __restrict__ bias,
    const float* __restrict__ g, const float* __restrict__ bta,
    float* __restrict__ h, bf16* __restrict__ y)
{
  int row = blockIdx.x;
  int tid = threadIdx.x;
  const long MN = (long)M_*HID_;
  float* hr = h + (long)row*HID_;
  float v[3];
#pragma unroll
  for (int j = 0; j < 3; ++j) {
    int c = tid + j*256;
    float a = hr[c] + bias[c];
    const float* pp = part + (long)row*HID_ + c;
#pragma unroll
    for (int z = 0; z < NZ; ++z) a += pp[(long)z*MN];
    v[j] = a;
    hr[c] = a;
  }
  float s = v[0] + v[1] + v[2];
  float ss = v[0]*v[0] + v[1]*v[1] + v[2]*v[2];
  for (int off = 32; off > 0; off >>= 1) {
    s  += __shfl_xor(s, off);
    ss += __shfl_xor(ss, off);
  }
  __shared__ float rs[4], rss[4];
  int w = tid / 64;
  if ((tid & 63) == 0) { rs[w] = s; rss[w] = ss; }
  __syncthreads();
  s  = rs[0] + rs[1] + rs[2] + rs[3];
  ss = rss[0] + rss[1] + rss[2] + rss[3];
  float mean = s * (1.0f/768.0f);
  float var  = ss * (1.0f/768.0f) - mean*mean;
  float rstd = rsqrtf(var + 1e-5f);
  bf16* yr = y + (long)row*HID_;
#pragma unroll
  for (int j = 0; j < 3; ++j) {
    int c = tid + j*256;
    yr[c] = __float2bfloat16((v[j] - mean)*rstd*g[c] + bta[c]);
  }
}

// ============================================================
// weight converts
// ============================================================
__global__ __launch_bounds__(256) void wconv_kernel(
    const float* __restrict__ W, bf16* __restrict__ Out,
    int K, int N, float scale)
{
  __shared__ float tile[32][33];
  int bx = blockIdx.x * 32;
  int by = blockIdx.y * 32;
  int tx = threadIdx.x & 31, ty = threadIdx.x >> 5;
#pragma unroll
  for (int r = 0; r < 32; r += 8)
    tile[ty + r][tx] = W[(long)(by + ty + r)*N + bx + tx];
  __syncthreads();
#pragma unroll
  for (int r = 0; r < 32; r += 8)
    Out[(long)(bx + ty + r)*K + by + tx] = __float2bfloat16(tile[tx][ty + r] * scale);
}

__global__ __launch_bounds__(256) void qkvconv_kernel(
    const float* __restrict__ wq, const float* __restrict__ wk,
    const float* __restrict__ wv, bf16* __restrict__ Out, float scale)
{
  const float* W = blockIdx.z == 0 ? wq : blockIdx.z == 1 ? wk : wv;
  float sc = blockIdx.z == 0 ? scale : 1.0f;
  __shared__ float tile[32][33];
  int bx = blockIdx.x * 32;
  int by = blockIdx.y * 32;
  int tx = threadIdx.x & 31, ty = threadIdx.x >> 5;
#pragma unroll
  for (int r = 0; r < 32; r += 8)
    tile[ty + r][tx] = W[(long)(by + ty + r)*768 + bx + tx];
  __syncthreads();
  bf16* O = Out + (long)blockIdx.z * 768 * 768;
#pragma unroll
  for (int r = 0; r < 32; r += 8)
    O[(long)(bx + ty + r)*768 + by + tx] = __float2bfloat16(tile[tx][ty + r] * sc);
}

__global__ __launch_bounds__(256) void qkvconv_all_kernel(
    const float* __restrict__ wq, const float* __restrict__ wk,
    const float* __restrict__ wv, bf16* __restrict__ wbuf, float scale)
{
  int z = blockIdx.z;
  int l = z / 3, which = z % 3;
  const float* W = (which == 0 ? wq : which == 1 ? wk : wv) + (size_t)l*768*768;
  float sc = which == 0 ? scale : 1.0f;
  __shared__ float tile[32][33];
  int bx = blockIdx.x * 32;
  int by = blockIdx.y * 32;
  int tx = threadIdx.x & 31, ty = threadIdx.x >> 5;
#pragma unroll
  for (int r = 0; r < 32; r += 8)
    tile[ty + r][tx] = W[(long)(by + ty + r)*768 + bx + tx];
  __syncthreads();
  bf16* O = wbuf + (size_t)l*WL_E_ + (size_t)which*768*768;
#pragma unroll
  for (int r = 0; r < 32; r += 8)
    O[(long)(bx + ty + r)*768 + by + tx] = __float2bfloat16(tile[tx][ty + r] * sc);
}

__global__ __launch_bounds__(256) void wconv_all_kernel(
    const float* __restrict__ Wb, bf16* __restrict__ Ob,
    int K, int N, long inStride, long outStride)
{
  int z = blockIdx.z;
  const float* W = Wb + (size_t)z * inStride;
  bf16* Out = Ob + (size_t)z * outStride;
  __shared__ float tile[32][33];
  int bx = blockIdx.x * 32;
  int by = blockIdx.y * 32;
  int tx = threadIdx.x & 31, ty = threadIdx.x >> 5;
#pragma unroll
  for (int r = 0; r < 32; r += 8)
    tile[ty + r][tx] = W[(long)(by + ty + r)*N + bx + tx];
  __syncthreads();
#pragma unroll
  for (int r = 0; r < 32; r += 8)
    Out[(long)(bx + ty + r)*K + by + tx] = __float2bfloat16(tile[tx][ty + r]);
}

__global__ __launch_bounds__(256) void biasqkv_kernel(
    const float* __restrict__ bq, const float* __restrict__ bk,
    const float* __restrict__ bv, float* __restrict__ bqkv, float scale)
{
  int idx = blockIdx.x * 256 + threadIdx.x;
  if (idx >= L_*2304) return;
  int l = idx / 2304, n = idx % 2304;
  int p = n / 768, nn = n % 768;
  float v = (p == 0) ? bq[l*768 + nn]*scale : (p == 1) ? bk[l*768 + nn] : bv[l*768 + nn];
  bqkv[idx] = v;
}

// ============================================================
// bf16 MFMA GEMM 64x64 (O-proj + fallbacks): ring-2, vmcnt 4/0.
// mode 0: bf16 out; 1: gelu->bf16; 2: +resid->fp32; 3: fp32 partial
// ============================================================
__device__ __forceinline__ void stage64k(
    const bf16* __restrict__ A, const bf16* __restrict__ Wt,
    bf16* Als, bf16* Bls, int bm, int bn, long ka, int M, int lda, int ldb, int tid)
{
  int r0 = tid >> 3, c = tid & 7;
#pragma unroll
  for (int p = 0; p < 2; ++p) {
    int row = p*32 + r0;
    int cs = c ^ (row & 7);
    int grow = bm + row; if (grow >= M) grow = M - 1;
    gload_lds16(A + (long)grow*lda + ka + cs*8, Als + (p*256 + (tid & ~63))*8);
    gload_lds16(Wt + (long)(bn + row)*ldb + ka + cs*8, Bls + (p*256 + (tid & ~63))*8);
  }
}

__global__ __launch_bounds__(256) void gemm64_kernel(
    const bf16* __restrict__ A, const bf16* __restrict__ Wt,
    const float* __restrict__ bias, const float* __restrict__ resid,
    void* __restrict__ Cout, int M, int N, int Klen, int lda, int ldb, int mode)
{
  constexpr int ASZ = 64*64;
  __shared__ bf16 Als[2*ASZ];
  __shared__ bf16 Bls[2*ASZ];
  int tid = threadIdx.x;
  int wid = tid >> 6, lane = tid & 63;

  int gx = gridDim.x;
  int nwg = gx * gridDim.y;
  int id = blockIdx.y * gx + blockIdx.x;
  int q = nwg >> 3, r = nwg & 7;
  int xcd = id & 7, off = id >> 3;
  int swz = (xcd < r) ? (xcd*(q+1) + off) : (r*(q+1) + (xcd - r)*q + off);
  int bm = (swz / gx) * 64, bn = (swz % gx) * 64;

  long koff = (long)blockIdx.z * Klen;
  int wr = wid >> 1, wc = wid & 1;
  int lr = lane & 15, kg = lane >> 4;

  int aoff[2][2], boff[2][2];
#pragma unroll
  for (int m = 0; m < 2; ++m) {
    int row = wr*32 + m*16 + lr;
#pragma unroll
    for (int hf = 0; hf < 2; ++hf) {
      int chunk = hf*4 + kg;
      aoff[m][hf] = (row*8 + (chunk ^ (row & 7)))*8;
    }
  }
#pragma unroll
  for (int n = 0; n < 2; ++n) {
    int col = wc*32 + n*16 + lr;
#pragma unroll
    for (int hf = 0; hf < 2; ++hf) {
      int chunk = hf*4 + kg;
      boff[n][hf] = (col*8 + (chunk ^ (col & 7)))*8;
    }
  }

  f32x4 acc[2][2];
#pragma unroll
  for (int m = 0; m < 2; ++m)
#pragma unroll
    for (int n = 0; n < 2; ++n)
      acc[m][n] = (f32x4){0.0f, 0.0f, 0.0f, 0.0f};

  int nt = Klen >> 6;
  stage64k(A, Wt, Als,       Bls,       bm, bn, koff,      M, lda, ldb, tid);
  stage64k(A, Wt, Als + ASZ, Bls + ASZ, bm, bn, koff + 64, M, lda, ldb, tid);

  int cur = 0;
  for (int t = 0; t < nt; ++t) {
    if (t + 1 < nt) VMCNT(4);
    else            VMCNT(0);
    __builtin_amdgcn_s_barrier();
    LDS_FENCE();
    bf16* Acur = Als + cur*ASZ;
    bf16* Bcur = Bls + cur*ASZ;
    short8 av[2][2], bv2[2][2];
#pragma unroll
    for (int m = 0; m < 2; ++m)
#pragma unroll
      for (int hf = 0; hf < 2; ++hf) av[m][hf] = *(const short8*)(Acur + aoff[m][hf]);
#pragma unroll
    for (int n = 0; n < 2; ++n)
#pragma unroll
      for (int hf = 0; hf < 2; ++hf) bv2[n][hf] = *(const short8*)(Bcur + boff[n][hf]);
#pragma unroll
    for (int hf = 0; hf < 2; ++hf)
#pragma unroll
      for (int m = 0; m < 2; ++m)
#pragma unroll
        for (int n = 0; n < 2; ++n)
          acc[m][n] = __builtin_amdgcn_mfma_f32_16x16x32_bf16(av[m][hf], bv2[n][hf], acc[m][n], 0, 0, 0);
    LDS_FENCE();
    __builtin_amdgcn_s_barrier();
    if (t + 2 < nt)
      stage64k(A, Wt, Als + cur*ASZ, Bls + cur*ASZ,
               bm, bn, koff + (long)(t+2)*64, M, lda, ldb, tid);
    cur ^= 1;
  }

#pragma unroll
  for (int n = 0; n < 2; ++n) {
    int col = bn + wc*32 + n*16 + lr;
    float bcol = (mode == 3) ? 0.0f : bias[col];
#pragma unroll
    for (int m = 0; m < 2; ++m) {
      f32x4 a = acc[m][n];
#pragma unroll
      for (int i = 0; i < 4; ++i) {
        int row = bm + wr*32 + m*16 + kg*4 + i;
        if (row < M) {
          float v = a[i] + bcol;
          if (mode == 1) v = 0.5f * v * (1.0f + erff(v * 0.70710678118654752f));
          if (mode == 2)
            ((float*)Cout)[(long)row*N + col] = v + resid[(long)row*N + col];
          else if (mode == 3)
            ((float*)Cout + (size_t)blockIdx.z*M*N)[(long)row*N + col] = v;
          else
            ((bf16*)Cout)[(long)row*N + col] = __float2bfloat16(v);
        }
      }
    }
  }
}

// ============================================================
// bf16 MFMA GEMM 128x128: 512 thr (8 waves, 2x4), wave tile 64x32,
// BK=64, ring-2 (64KB LDS), counted vmcnt 4/0, XOR swizzle, XCD swizzle.
// koff = blockIdx.z * Klen (split-K support).
// mode 0: bf16 out; 1: gelu->bf16; 3: fp32 partial (no bias)
// ============================================================
__device__ __forceinline__ void stage128k(
    const bf16* __restrict__ A, const bf16* __restrict__ Wt,
    bf16* Als, bf16* Bls, int bm, int bn, long ka, int M, int lda, int ldb, int tid)
{
  int r0 = tid >> 3, c = tid & 7;   // r0: 0..63, c: 0..7
#pragma unroll
  for (int p = 0; p < 2; ++p) {
    int row = p*64 + r0;
    int cs = c ^ (row & 7);
    int grow = bm + row; if (grow >= M) grow = M - 1;
    gload_lds16(A + (long)grow*lda + ka + cs*8, Als + (p*512 + (tid & ~63))*8);
    gload_lds16(Wt + (long)(bn + row)*ldb + ka + cs*8, Bls + (p*512 + (tid & ~63))*8);
  }
}

__global__ __launch_bounds__(512) void gemm128_kernel(
    const bf16* __restrict__ A, const bf16* __restrict__ Wt,
    const float* __restrict__ bias, void* __restrict__ Cout,
    int M, int N, int Klen, int lda, int ldb, int mode)
{
  constexpr int ASZ = 128*64;
  __shared__ bf16 Als[2*ASZ];
  __shared__ bf16 Bls[2*ASZ];
  int tid = threadIdx.x;
  int wid = tid >> 6, lane = tid & 63;

  int gx = gridDim.x;
  int nwg = gx * gridDim.y;
  int id = blockIdx.y * gx + blockIdx.x;
  int q = nwg >> 3, r = nwg & 7;
  int xcd = id & 7, off = id >> 3;
  int swz = (xcd < r) ? (xcd*(q+1) + off) : (r*(q+1) + (xcd - r)*q + off);
  int bm = (swz / gx) * 128, bn = (swz % gx) * 128;

  long koff = (long)blockIdx.z * Klen;
  int wr = wid >> 2, wc = wid & 3;           // 2 x 4 waves
  int lr = lane & 15, kg = lane >> 4;

  int aoff[4][2], boff[2][2];
#pragma unroll
  for (int m = 0; m < 4; ++m) {
    int row = wr*64 + m*16 + lr;
#pragma unroll
    for (int hf = 0; hf < 2; ++hf) {
      int chunk = hf*4 + kg;
      aoff[m][hf] = (row*8 + (chunk ^ (row & 7)))*8;
    }
  }
#pragma unroll
  for (int n = 0; n < 2; ++n) {
    int col = wc*32 + n*16 + lr;
#pragma unroll
    for (int hf = 0; hf < 2; ++hf) {
      int chunk = hf*4 + kg;
      boff[n][hf] = (col*8 + (chunk ^ (col & 7)))*8;
    }
  }

  f32x4 acc[4][2];
#pragma unroll
  for (int m = 0; m < 4; ++m)
#pragma unroll
    for (int n = 0; n < 2; ++n)
      acc[m][n] = (f32x4){0.0f, 0.0f, 0.0f, 0.0f};

  int nt = Klen >> 6;
  stage128k(A, Wt, Als,       Bls,       bm, bn, koff,      M, lda, ldb, tid);
  stage128k(A, Wt, Als + ASZ, Bls + ASZ, bm, bn, koff + 64, M, lda, ldb, tid);

  int cur = 0;
  for (int t = 0; t < nt; ++t) {
    if (t + 1 < nt) VMCNT(4);
    else            VMCNT(0);
    __builtin_amdgcn_s_barrier();
    LDS_FENCE();
    bf16* Acur = Als + cur*ASZ;
    bf16* Bcur = Bls + cur*ASZ;
    short8 av[4][2], bv2[2][2];
#pragma unroll
    for (int m = 0; m < 4; ++m)
#pragma unroll
      for (int hf = 0; hf < 2; ++hf) av[m][hf] = *(const short8*)(Acur + aoff[m][hf]);
#pragma unroll
    for (int n = 0; n < 2; ++n)
#pragma unroll
      for (int hf = 0; hf < 2; ++hf) bv2[n][hf] = *(const short8*)(Bcur + boff[n][hf]);
#pragma unroll
    for (int hf = 0; hf < 2; ++hf)
#pragma unroll
      for (int m = 0; m < 4; ++m)
#pragma unroll
        for (int n = 0; n < 2; ++n)
          acc[m][n] = __builtin_amdgcn_mfma_f32_16x16x32_bf16(av[m][hf], bv2[n][hf], acc[m][n], 0, 0, 0);
    LDS_FENCE();
    __builtin_amdgcn_s_barrier();
    if (t + 2 < nt)
      stage128k(A, Wt, Als + cur*ASZ, Bls + cur*ASZ,
                bm, bn, koff + (long)(t+2)*64, M, lda, ldb, tid);
    cur ^= 1;
  }

#pragma unroll
  for (int n = 0; n < 2; ++n) {
    int col = bn + wc*32 + n*16 + lr;
    float bcol = (mode == 3) ? 0.0f : bias[col];
#pragma unroll
    for (int m = 0; m < 4; ++m) {
      f32x4 a = acc[m][n];
#pragma unroll
      for (int i = 0; i < 4; ++i) {
        int row = bm + wr*64 + m*16 + kg*4 + i;
        if (row < M) {
          float v = a[i] + bcol;
          if (mode == 1) v = 0.5f * v * (1.0f + erff(v * 0.70710678118654752f));
          if (mode == 3)
            ((float*)Cout + (size_t)blockIdx.z*M*N)[(long)row*N + col] = v;
          else
            ((bf16*)Cout)[(long)row*N + col] = __float2bfloat16(v);
        }
      }
    }
  }
}

// ============================================================
// MFMA fused attention: ONE 8-wave block per (b,h). (R13-proven)
// ============================================================
template<typename GT>
__global__ __launch_bounds__(512) void attn_kernel(
    const bf16* __restrict__ qkv, const GT* __restrict__ gab,
    bf16* __restrict__ ob)
{
  int bh = blockIdx.x;
  int b = bh >> 5, hh = bh & 31;
  __shared__ bf16 kl[SP_*32];
  __shared__ bf16 vt[32*KP_];
  __shared__ bf16 pl[8][16*KP_];
  int tid = threadIdx.x;
  int wv = tid >> 6, lane = tid & 63;
  const short8 z8 = (short8){0,0,0,0,0,0,0,0};

  for (int idx = tid; idx < 32*KP_/8; idx += 512)
    *(short8*)&vt[idx*8] = z8;
  const bf16* qbase = qkv + (long)b*S_*2304 + hh*24;
  for (int u = tid; u < SP_*4; u += 512) {
    int row = u >> 2, c8 = u & 3;
    short8 kv = z8;
    if (row < S_ && c8 < 3)
      kv = *(const short8*)(qbase + (long)row*2304 + 768 + c8*8);
    int cs = c8 ^ ((row >> 1) & 3);
    *(short8*)&kl[row*32 + cs*8] = kv;
  }
  __syncthreads();
  for (int u = tid; u < S_*3; u += 512) {
    int kj = u / 3, c8 = u % 3;
    short8 vv = *(const short8*)(qbase + (long)kj*2304 + 1536 + c8*8);
    int kb = kj & 7, kh = kj >> 3;
#pragma unroll
    for (int e = 0; e < 8; ++e) {
      int c = c8*8 + e;
      int ch = kh ^ ((c >> 1) & 3);
      short sv = vv[e];
      vt[c*KP_ + ch*8 + kb] = *reinterpret_cast<bf16*>(&sv);
    }
  }
  __syncthreads();

  int l15 = lane & 15, l4 = lane >> 4;

  short8 bvf[5][2];
#pragma unroll
  for (int kc = 0; kc < 5; ++kc)
#pragma unroll
    for (int ntc = 0; ntc < 2; ++ntc) {
      int col = ntc*16 + l15;
      int ch = (kc*4 + l4) ^ ((col >> 1) & 3);
      bvf[kc][ntc] = *(const short8*)&vt[col*KP_ + ch*8];
    }

  bf16* plw = pl[wv];
  for (int idx = lane; idx < 16*KP_/8; idx += 64)
    *(short8*)&plw[idx*8] = z8;

  const GT* gb = gab + (long)(b*H_ + hh)*S_*S_;

  for (int rep = 0; rep < 2; ++rep) {
    int mf = (rep == 0) ? wv : ((wv == 0) ? 8 : -1);
    if (mf < 0) continue;
    int qb0 = mf * 16;
    int qrow = qb0 + l15;
    short8 aq = z8;
    if (qrow < S_ && l4 < 3)
      aq = *(const short8*)(qbase + (long)qrow*2304 + l4*8);
    f32x4 sc[9];
#pragma unroll
    for (int nt = 0; nt < 9; ++nt) {
      int krow = nt*16 + l15;
      int kch = l4 ^ ((krow >> 1) & 3);
      short8 bk = *(const short8*)&kl[krow*32 + kch*8];
      sc[nt] = __builtin_amdgcn_mfma_f32_16x16x32_bf16(aq, bk, (f32x4){0,0,0,0}, 0, 0, 0);
    }
    float mx[4] = {-1e30f,-1e30f,-1e30f,-1e30f};
#pragma unroll
    for (int nt = 0; nt < 9; ++nt) {
      int kj = nt*16 + l15;
      int kjc = kj < S_ ? kj : 0;
#pragma unroll
      for (int i = 0; i < 4; ++i) {
        int q = qb0 + l4*4 + i;
        int qc = q < S_ ? q : 0;
        float v = sc[nt][i] + gld(&gb[(long)qc*S_ + kjc]);
        if (kj >= S_) v = -1e30f;
        sc[nt][i] = v;
        mx[i] = fmaxf(mx[i], v);
      }
    }
#pragma unroll
    for (int i = 0; i < 4; ++i) {
      mx[i] = fmaxf(mx[i], __shfl_xor(mx[i], 1));
      mx[i] = fmaxf(mx[i], __shfl_xor(mx[i], 2));
      mx[i] = fmaxf(mx[i], __shfl_xor(mx[i], 4));
      mx[i] = fmaxf(mx[i], __shfl_xor(mx[i], 8));
    }
    float sum[4] = {0.f,0.f,0.f,0.f};
#pragma unroll
    for (int nt = 0; nt < 9; ++nt)
#pragma unroll
      for (int i = 0; i < 4; ++i) {
        float e = __expf(sc[nt][i] - mx[i]);
        sc[nt][i] = e;
        sum[i] += e;
      }
#pragma unroll
    for (int i = 0; i < 4; ++i) {
      sum[i] += __shfl_xor(sum[i], 1);
      sum[i] += __shfl_xor(sum[i], 2);
      sum[i] += __shfl_xor(sum[i], 4);
      sum[i] += __shfl_xor(sum[i], 8);
    }
#pragma unroll
    for (int nt = 0; nt < 9; ++nt) {
      int kj = nt*16 + l15;
#pragma unroll
      for (int i = 0; i < 4; ++i) {
        int q = l4*4 + i;
        int ch = (kj >> 3) ^ ((q >> 1) & 3);
        plw[q*KP_ + ch*8 + (kj & 7)] = __float2bfloat16(sc[nt][i]);
      }
    }
    f32x4 av[2] = {(f32x4){0,0,0,0}, (f32x4){0,0,0,0}};
#pragma unroll
    for (int kc = 0; kc < 5; ++kc) {
      int ch = (kc*4 + l4) ^ ((l15 >> 1) & 3);
      short8 ap = *(const short8*)&plw[l15*KP_ + ch*8];
#pragma unroll
      for (int ntc = 0; ntc < 2; ++ntc)
        av[ntc] = __builtin_amdgcn_mfma_f32_16x16x32_bf16(ap, bvf[kc][ntc], av[ntc], 0, 0, 0);
    }
#pragma unroll
    for (int ntc = 0; ntc < 2; ++ntc) {
      int c = ntc*16 + l15;
      if (c < 24) {
#pragma unroll
        for (int i = 0; i < 4; ++i) {
          int q = qb0 + l4*4 + i;
          if (q < S_)
            ob[(long)(b*S_ + q)*768 + hh*24 + c] = __float2bfloat16(av[ntc][i] / sum[i]);
        }
      }
    }
  }
}

// ============================================================
// final
// ============================================================
__global__ __launch_bounds__(256) void final_kernel(
    const float* __restrict__ h, const float* __restrict__ fg,
    const float* __restrict__ fb, const float* __restrict__ pw,
    const float* __restrict__ pb, float* __restrict__ out)
{
  int b = blockIdx.x;
  int tid = threadIdx.x;
  const float* xr = h + (long)b * S_ * HID_;
  float x0 = xr[tid], x1 = xr[tid + 256], x2 = xr[tid + 512];
  float s = x0 + x1 + x2;
  float ss = x0*x0 + x1*x1 + x2*x2;
  for (int off = 32; off > 0; off >>= 1) {
    s  += __shfl_xor(s, off);
    ss += __shfl_xor(ss, off);
  }
  __shared__ float rs[4], rss[4], rd[4];
  int w = tid / 64;
  if ((tid & 63) == 0) { rs[w] = s; rss[w] = ss; }
  __syncthreads();
  s  = rs[0] + rs[1] + rs[2] + rs[3];
  ss = rss[0] + rss[1] + rss[2] + rss[3];
  float mean = s * (1.0f/768.0f);
  float var  = ss * (1.0f/768.0f) - mean*mean;
  float rstd = rsqrtf(var + 1e-5f);
  float d0 = ((x0 - mean)*rstd*fg[tid]       + fb[tid])       * pw[tid];
  float d1 = ((x1 - mean)*rstd*fg[tid + 256] + fb[tid + 256]) * pw[tid + 256];
  float d2 = ((x2 - mean)*rstd*fg[tid + 512] + fb[tid + 512]) * pw[tid + 512];
  float pd = d0 + d1 + d2;
  for (int off = 32; off > 0; off >>= 1) pd += __shfl_xor(pd, off);
  if ((tid & 63) == 0) rd[w] = pd;
  __syncthreads();
  if (tid == 0) out[b] = rd[0] + rd[1] + rd[2] + rd[3] + pb[0];
}

// ============================================================
extern "C" void kernel_launch(void* const* d_in, const int* in_sizes, int n_in,
                              void* d_out, int out_size, void* d_ws, size_t ws_size,
                              hipStream_t stream)
{
  const float* attn_bias   = (const float*)d_in[0];
  const int*   spatial_pos = (const int*)d_in[1];
  const int*   x           = (const int*)d_in[2];
  const int*   in_degree   = (const int*)d_in[3];
  const int*   out_degree  = (const int*)d_in[4];
  const int*   edge_input  = (const int*)d_in[5];
  const float* atom_emb    = (const float*)d_in[6];
  const float* edge_emb    = (const float*)d_in[7];
  const float* edge_dis    = (const float*)d_in[8];
  const float* spatial_emb = (const float*)d_in[9];
  const float* in_deg_emb  = (const float*)d_in[10];
  const float* out_deg_emb = (const float*)d_in[11];
  const float* graph_token = (const float*)d_in[12];
  const float* gt_vd       = (const float*)d_in[13];
  const float* ln1_g = (const float*)d_in[14];
  const float* ln1_b = (const float*)d_in[15];
  const float* wq = (const float*)d_in[16];
  const float* bq = (const float*)d_in[17];
  const float* wk = (const float*)d_in[18];
  const float* bk = (const float*)d_in[19];
  const float* wv = (const float*)d_in[20];
  const float* bv = (const float*)d_in[21];
  const float* wo = (const float*)d_in[22];
  const float* bo = (const float*)d_in[23];
  const float* ln2_g = (const float*)d_in[24];
  const float* ln2_b = (const float*)d_in[25];
  const float* w1 = (const float*)d_in[26];
  const float* b1 = (const float*)d_in[27];
  const float* w2 = (const float*)d_in[28];
  const float* b2 = (const float*)d_in[29];
  const float* final_g = (const float*)d_in[30];
  const float* final_b = (const float*)d_in[31];
  const float* proj_w  = (const float*)d_in[32];
  const float* proj_b  = (const float*)d_in[33];

  float* out = (float*)d_out;

  const float scale = 0.20412414523193154f;  // 24^-0.5
  const long GAB_N = (long)B_*H_*S_*S_;      // 8,520,192
  const size_t PART_B = (size_t)4 * M_ * 768 * 4;   // 25.4 MB

  char* dws = (char*)d_ws;
  char* p = dws;
  float* gab  = (float*)p;  p += GAB_N*4;
  float* h    = (float*)p;  p += (long)M_*HID_*4;
  bf16*  y    = (bf16*)p;   p += (long)M_*HID_*2;
  bf16*  qkv  = (bf16*)p;   // ffn aliases qkv+ob
  bf16*  ffn  = qkv;
  p += (long)M_*2304*2;
  bf16*  ob   = (bf16*)p;   p += (long)M_*HID_*2;
  float* Ftab = (float*)p;  p += (long)5*1537*32*4;
  float* bqkv = (float*)p;  p += (long)L_*2304*4;

  // optional split-K partial buffer
  float* part = (float*)p;
  bool psplit = ws_size >= (size_t)(p - dws) + PART_B + WL_E_*2;
  if (psplit) p += PART_B;
  // optional bf16 gab
  bf16* gabh = (bf16*)p;
  bool g16 = ws_size >= (size_t)(p - dws) + (size_t)GAB_N*2 + WL_E_*2;
  if (g16) p += GAB_N*2;
  // weight buffer
  bf16* wbuf = (bf16*)p;
  bool full = ws_size >= (size_t)(p - dws) + (size_t)L_ * WL_E_ * 2;

  // ---- setup ----
  const int PB = 2*S_ - 1;
  gab_bound_kernel<<<(B_*H_*PB + 255)/256, 256, 0, stream>>>(
      attn_bias, gt_vd, gab, g16 ? gabh : nullptr);
  ftab_kernel<<<(5*1537 + 7)/8, 256, 0, stream>>>(edge_emb, edge_dis, Ftab);
  edge_kernel<<<B_*N_, 256, 0, stream>>>(
      edge_input, Ftab, spatial_pos, spatial_emb, attn_bias, gab,
      g16 ? gabh : nullptr);
  nodefeat_ln_kernel<<<M_, 256, 0, stream>>>(
      x, in_degree, out_degree, atom_emb, in_deg_emb, out_deg_emb, graph_token,
      ln1_g, ln1_b, h, y);
  biasqkv_kernel<<<(L_*2304 + 255)/256, 256, 0, stream>>>(bq, bk, bv, bqkv, scale);

  if (full) {
    qkvconv_all_kernel<<<dim3(24,24,3*L_), 256, 0, stream>>>(wq, wk, wv, wbuf, scale);
    wconv_all_kernel<<<dim3(24,24,L_), 256, 0, stream>>>(
        wo, wbuf + WQKV_E, 768, 768, (long)768*768, (long)WL_E_);
    wconv_all_kernel<<<dim3(96,24,L_), 256, 0, stream>>>(
        w1, wbuf + WQKV_E + WO_E, 768, 3072, (long)768*3072, (long)WL_E_);
    wconv_all_kernel<<<dim3(24,96,L_), 256, 0, stream>>>(
        w2, wbuf + WQKV_E + WO_E + W1_E, 3072, 768, (long)3072*768, (long)WL_E_);
  }

  const int MT  = (M_ + 63)/64;              // 33
  const int MT2 = (M_ + 127)/128;            // 17
  dim3 gQKV(2304/128, MT2);                  // 18 x 17 (128^2)
  dim3 gF1 (3072/128, MT2);                  // 24 x 17 (128^2)
  dim3 gO2 (768/64,  MT, 2);                 // split-K2 (O-proj, 64^2, Klen=384)
  dim3 gO  (768/64,  MT);
  dim3 gF2 (768/128, MT2, 4);                // split-K4 (FFN2, 128^2, Klen=768)
  dim3 gF2f(768/64,  MT);                    // fallback (no psplit)
  dim3 cQKV(768/32, 768/32, 3);
  dim3 cO  (768/32, 768/32);
  dim3 cW1 (3072/32, 768/32);
  dim3 cW2 (768/32, 3072/32);

  auto wptr = [&](int l) { return wbuf + (full ? (size_t)l : 0) * WL_E_; };
  auto conv = [&](int l) {
    bf16* W = wptr(l);
    qkvconv_kernel<<<cQKV, 256, 0, stream>>>(
        wq + (size_t)l*HID_*HID_, wk + (size_t)l*HID_*HID_, wv + (size_t)l*HID_*HID_,
        W, scale);
    wconv_kernel<<<cO, 256, 0, stream>>>(wo + (size_t)l*HID_*HID_, W + WQKV_E, 768, 768, 1.0f);
    wconv_kernel<<<cW1, 256, 0, stream>>>(w1 + (size_t)l*HID_*FFN_, W + WQKV_E + WO_E, 768, 3072, 1.0f);
    wconv_kernel<<<cW2, 256, 0, stream>>>(w2 + (size_t)l*FFN_*HID_, W + WQKV_E + WO_E + W1_E, 3072, 768, 1.0f);
  };

  for (int l = 0; l < L_; ++l) {
    if (!full) conv(l);
    bf16* W = wptr(l);
    bf16* Wqkvt = W;
    bf16* Wot   = W + WQKV_E;
    bf16* W1t   = W + WQKV_E + WO_E;
    bf16* W2t   = W + WQKV_E + WO_E + W1_E;

    if (l > 0 && !psplit)
      ln_kernel<<<M_, 256, 0, stream>>>(h, ln1_g + l*HID_, ln1_b + l*HID_, y);

    gemm128_kernel<<<gQKV, 512, 0, stream>>>(
        y, Wqkvt, bqkv + l*2304, qkv, M_, 2304, 768, 768, 768, 0);
    if (g16)
      attn_kernel<bf16><<<B_*H_, 512, 0, stream>>>(qkv, gabh, ob);
    else
      attn_kernel<float><<<B_*H_, 512, 0, stream>>>(qkv, gab, ob);

    if (psplit) {
      gemm64_kernel<<<gO2, 256, 0, stream>>>(
          ob, Wot, nullptr, nullptr, part, M_, 768, 384, 768, 768, 3);
      addln_kernel<2><<<M_, 256, 0, stream>>>(
          part, bo + l*HID_, ln2_g + l*HID_, ln2_b + l*HID_, h, y);
    } else {
      gemm64_kernel<<<gO, 256, 0, stream>>>(
          ob, Wot, bo + l*HID_, h, h, M_, 768, 768, 768, 768, 2);
      ln_kernel<<<M_, 256, 0, stream>>>(h, ln2_g + l*HID_, ln2_b + l*HID_, y);
    }

    gemm128_kernel<<<gF1, 512, 0, stream>>>(
        y, W1t, b1 + l*FFN_, ffn, M_, 3072, 768, 768, 768, 1);

    if (psplit) {
      gemm128_kernel<<<gF2, 512, 0, stream>>>(
          ffn, W2t, nullptr, part, M_, 768, 768, 3072, 3072, 3);
      int ln = (l + 1 < L_) ? l + 1 : 0;   // last layer: y unused afterward
      addln_kernel<4><<<M_, 256, 0, stream>>>(
          part, b2 + l*HID_, ln1_g + ln*HID_, ln1_b + ln*HID_, h, y);
    } else {
      gemm64_kernel<<<gF2f, 256, 0, stream>>>(
          ffn, W2t, b2 + l*HID_, h, h, M_, 768, 3072, 3072, 3072, 2);
    }
  }

  final_kernel<<<B_, 256, 0, stream>>>(h, final_g, final_b, proj_w, proj_b, out);
}